// Round 3
// baseline (277.319 us; speedup 1.0000x reference)
//
#include <hip/hip_runtime.h>
#include <hip/hip_bf16.h>

#define B_TOTAL 4096
#define MBATCH 32

typedef short short8 __attribute__((ext_vector_type(8)));
typedef float f32x4 __attribute__((ext_vector_type(4)));

__device__ __forceinline__ unsigned short rne_bf16(float x) {
    unsigned int u = __float_as_uint(x);
    unsigned int r = (u + 0x7fffu + ((u >> 16) & 1u)) >> 16;
    return (unsigned short)r;
}
__device__ __forceinline__ float bf16_to_f(unsigned short h) {
    return __uint_as_float(((unsigned int)h) << 16);
}
__device__ __forceinline__ unsigned int cvt2bf(float lo, float hi) {
    unsigned int r;
    asm("v_cvt_pk_bf16_f32 %0, %1, %2" : "=v"(r) : "v"(lo), "v"(hi));
    return r;   // low16 = bf16(lo), high16 = bf16(hi), RNE
}
__device__ __forceinline__ float fast_sigm(float x) {
    return __builtin_amdgcn_rcpf(1.0f + __expf(-x));
}
__device__ __forceinline__ float fast_tanh(float x) {
    return 1.0f - 2.0f * __builtin_amdgcn_rcpf(1.0f + __expf(2.0f * x));
}
__device__ __forceinline__ void cell_update(const f32x4 z, float& c, float& h) {
    const float ig = fast_sigm(z[0]);
    const float fg = fast_sigm(z[1]);
    const float gg = fast_tanh(z[2]);
    const float og = fast_sigm(z[3]);
    c = fg * c + ig * gg;
    h = og * fast_tanh(c);
}

// ---------------- Kernel A: neighbor mean ----------------
__global__ __launch_bounds__(256) void k_neighbor_mean(
    const float* __restrict__ matrix,   // [B,64,64]
    const float* __restrict__ features, // [B,64,6]
    float* __restrict__ upd)            // [B,64,6]
{
    __shared__ float adj[64][65];
    __shared__ float fx[64][6];
    const int b = blockIdx.x;
    const int tid = threadIdx.x;
    const float* mb_ = matrix + (size_t)b * 4096;
    for (int idx = tid; idx < 4096; idx += 256) adj[idx >> 6][idx & 63] = mb_[idx];
    const float* fb = features + (size_t)b * 384;
    for (int idx = tid; idx < 384; idx += 256) fx[idx / 6][idx % 6] = fb[idx];
    __syncthreads();
    if (tid < 64) {
        const int i = tid;
        float s0=0,s1=0,s2=0,s3=0,s4=0,s5=0,cnt=0;
        for (int j = 0; j < 64; j++) {
            float m = adj[i][j] > 0.0f ? 1.0f : 0.0f;
            cnt += m;
            s0 += m*fx[j][0]; s1 += m*fx[j][1]; s2 += m*fx[j][2];
            s3 += m*fx[j][3]; s4 += m*fx[j][4]; s5 += m*fx[j][5];
        }
        const float inv = 1.0f / (cnt + 1.0f);
        float* o = upd + (size_t)b * 384 + i * 6;
        o[0]=(s0+fx[i][0])*inv; o[1]=(s1+fx[i][1])*inv; o[2]=(s2+fx[i][2])*inv;
        o[3]=(s3+fx[i][3])*inv; o[4]=(s4+fx[i][4])*inv; o[5]=(s5+fx[i][5])*inv;
    }
}

// ---------------- Kernel W: weights -> A-fragment layout ----------------
// Aw[dir 2][mtg 32][kc 5][s 2][lane 64][e 8] bf16  (327680 ushorts)
// kc<4 : A'(n,k)=Wh[j][kc*32+8*lhi+e], s=0 hi / s=1 lo residual
// kc==4, s=0 (awU1): lhi0: e<6 Wi_hi[j][e], e6 bias_hi, e7 0 ; lhi1: e<6 Wi_hi[j][e] else 0 ; lhi>=2: 0
// kc==4, s=1 (awU2): lhi0: e<6 Wi_lo[j][e], e6 bias_lo, e7 0 ; else 0
// n = mtg*16+(l&15), gate-interleaved: j = (n&3)*128 + (n>>2)
__global__ __launch_bounds__(256) void k_wprep2(
    const float* __restrict__ Wi_f, const float* __restrict__ Wh_f,
    const float* __restrict__ bi_f, const float* __restrict__ bh_f,
    const float* __restrict__ Wi_b, const float* __restrict__ Wh_b,
    const float* __restrict__ bi_b, const float* __restrict__ bh_b,
    unsigned short* __restrict__ Aw)
{
    const int idx = blockIdx.x * 256 + threadIdx.x;   // 0..327679
    const int dir = idx / 163840;
    int r   = idx % 163840;
    const int mtg = r / 5120;  r %= 5120;
    const int kc  = r / 1024;  r %= 1024;
    const int s   = r >> 9;
    const int l   = (r >> 3) & 63;
    const int e   = r & 7;
    const int lhi = l >> 4;
    const int n   = mtg * 16 + (l & 15);
    const int j   = (n & 3) * 128 + (n >> 2);
    const float* Wh = dir ? Wh_b : Wh_f;
    const float* Wi = dir ? Wi_b : Wi_f;
    const float* bi = dir ? bi_b : bi_f;
    const float* bh = dir ? bh_b : bh_f;
    float w = 0.0f;
    bool want_lo = (s == 1);
    if (kc < 4) {
        w = Wh[j * 128 + kc * 32 + 8 * lhi + e];
    } else {
        if (s == 0) {   // awU1: hi weights in both k-halves
            if (lhi == 0)      w = (e < 6) ? Wi[j * 6 + e] : (e == 6 ? bi[j] + bh[j] : 0.0f);
            else if (lhi == 1) w = (e < 6) ? Wi[j * 6 + e] : 0.0f;
            want_lo = false;
        } else {        // awU2: lo residuals, k 0..7 only
            if (lhi == 0)      w = (e < 6) ? Wi[j * 6 + e] : (e == 6 ? bi[j] + bh[j] : 0.0f);
            want_lo = true;
        }
    }
    const unsigned short hi = rne_bf16(w);
    Aw[idx] = want_lo ? rne_bf16(w - bf16_to_f(hi)) : hi;
}

// ---------------- Kernel B: MFMA bi-LSTM scan, double-buffered h ----------------
// grid (128, 2), block 512 (8 waves). Step s: reads h(s-1) from buf[(s+1)&1], writes h(s) to buf[s&1].
__global__ __launch_bounds__(512, 2) void k_lstm3(
    const float* __restrict__ upd,          // [4096][64][6]
    const unsigned short* __restrict__ Aw,  // [2][32][5][2][64][8]
    float* __restrict__ hout)               // [2][4096][128]
{
    // H layout: byte = plane*16384 + buf*8192 + b*256 + swz_chunk*16 + (hu&7)*2
    // plane 0 = hi, plane 1 = lo  (lo reachable from hi addr via ds offset:16384)
    __shared__ unsigned short H[2][2][4096];    // 32 KB
    const int tid  = threadIdx.x;
    const int wave = tid >> 6;
    const int lane = tid & 63;
    const int dir  = blockIdx.y;
    const int b0   = blockIdx.x * MBATCH;
    const int l15  = lane & 15;
    const int lhi  = lane >> 4;
    char* Hb = (char*)H;

    // persistent weight A-fragments: 4mt x (4kc x 2 + awU 2) = 160 VGPRs
    short8 aw[4][4][2], awU[4][2];
    {
        const unsigned short* base = Aw + (size_t)dir * 163840;
        #pragma unroll
        for (int mt = 0; mt < 4; mt++) {
            const int mtg = wave * 4 + mt;
            #pragma unroll
            for (int kc = 0; kc < 4; kc++)
                #pragma unroll
                for (int s = 0; s < 2; s++)
                    aw[mt][kc][s] = *(const short8*)(base + (((size_t)(mtg * 5 + kc) * 2 + s) * 64 + lane) * 8);
            #pragma unroll
            for (int s = 0; s < 2; s++)
                awU[mt][s] = *(const short8*)(base + (((size_t)(mtg * 5 + 4) * 2 + s) * 64 + lane) * 8);
        }
    }

    // precomputed LDS byte addresses (hi plane; lo = +16384; buf toggle = XOR 0x2000)
    int raddr[2][4], waddr[4][2];
    #pragma unroll
    for (int nt = 0; nt < 2; nt++) {
        const int b = nt * 16 + l15;
        #pragma unroll
        for (int kc = 0; kc < 4; kc++)
            raddr[nt][kc] = b * 256 + (((kc * 4 + lhi) ^ (b & 7)) << 4) + 8192;  // rbuf=1 at s=0
    }
    #pragma unroll
    for (int mt = 0; mt < 4; mt++)
        #pragma unroll
        for (int nt = 0; nt < 2; nt++) {
            const int b  = nt * 16 + l15;
            const int hu = wave * 16 + mt * 4 + lhi;
            waddr[mt][nt] = b * 256 + ((((hu >> 3) ^ (b & 7))) << 4) + (hu & 7) * 2;  // wbuf=0 at s=0
        }

    // zero buf1 of both planes (read target of step 0)
    #pragma unroll
    for (int i = 0; i < 4; i++) {
        ((int*)Hb)[2048 + tid + 512 * i] = 0;   // hi, buf1
        ((int*)Hb)[6144 + tid + 512 * i] = 0;   // lo, buf1
    }
    float c[8];
    #pragma unroll
    for (int p = 0; p < 8; p++) c[p] = 0.0f;

    const float* ubase[2];
    ubase[0] = upd + (size_t)(b0 + l15) * 384;
    ubase[1] = upd + (size_t)(b0 + 16 + l15) * 384;

    __syncthreads();

    const f32x4 zero4 = {0.0f, 0.0f, 0.0f, 0.0f};
    const short8 zero8 = {0,0,0,0,0,0,0,0};

    #pragma unroll 1
    for (int s = 0; s < 64; ++s) {
        const int t = dir ? (63 - s) : s;

        // issue u loads early (consumed at chain tail)
        float2 ua[2][3];
        if (lhi < 2) {
            #pragma unroll
            for (int nt = 0; nt < 2; nt++) {
                const float2* p = (const float2*)(ubase[nt] + t * 6);
                ua[nt][0] = p[0]; ua[nt][1] = p[1]; ua[nt][2] = p[2];
            }
        }

        // h-recurrence MFMAs (3-pass split precision)
        f32x4 acc[4][2];
        #pragma unroll
        for (int kc = 0; kc < 4; kc++) {
            const short8 fh0 = *(const short8*)(Hb + raddr[0][kc]);
            const short8 fl0 = *(const short8*)(Hb + raddr[0][kc] + 16384);
            const short8 fh1 = *(const short8*)(Hb + raddr[1][kc]);
            const short8 fl1 = *(const short8*)(Hb + raddr[1][kc] + 16384);
            #pragma unroll
            for (int mt = 0; mt < 4; mt++) {
                f32x4 a0 = __builtin_amdgcn_mfma_f32_16x16x32_bf16(aw[mt][kc][0], fh0, kc == 0 ? zero4 : acc[mt][0], 0, 0, 0);
                a0 = __builtin_amdgcn_mfma_f32_16x16x32_bf16(aw[mt][kc][0], fl0, a0, 0, 0, 0);
                acc[mt][0] = __builtin_amdgcn_mfma_f32_16x16x32_bf16(aw[mt][kc][1], fh0, a0, 0, 0, 0);
                f32x4 a1 = __builtin_amdgcn_mfma_f32_16x16x32_bf16(aw[mt][kc][0], fh1, kc == 0 ? zero4 : acc[mt][1], 0, 0, 0);
                a1 = __builtin_amdgcn_mfma_f32_16x16x32_bf16(aw[mt][kc][0], fl1, a1, 0, 0, 0);
                acc[mt][1] = __builtin_amdgcn_mfma_f32_16x16x32_bf16(aw[mt][kc][1], fh1, a1, 0, 0, 0);
            }
        }

        // u-path: build B-fragments (hi in k0..7, lo in k8..15) and fold in (2 MFMAs per acc)
        short8 f1[2], f2[2];
        #pragma unroll
        for (int nt = 0; nt < 2; nt++) {
            int4 w = {0, 0, 0, 0};
            if (lhi == 0) {
                w.x = (int)cvt2bf(ua[nt][0].x, ua[nt][0].y);
                w.y = (int)cvt2bf(ua[nt][1].x, ua[nt][1].y);
                w.z = (int)cvt2bf(ua[nt][2].x, ua[nt][2].y);
                w.w = 0x3f80;
            } else if (lhi == 1) {
                const unsigned p0 = cvt2bf(ua[nt][0].x, ua[nt][0].y);
                const unsigned p1 = cvt2bf(ua[nt][1].x, ua[nt][1].y);
                const unsigned p2 = cvt2bf(ua[nt][2].x, ua[nt][2].y);
                const float r0 = ua[nt][0].x - __uint_as_float(p0 << 16);
                const float r1 = ua[nt][0].y - __uint_as_float(p0 & 0xffff0000u);
                const float r2 = ua[nt][1].x - __uint_as_float(p1 << 16);
                const float r3 = ua[nt][1].y - __uint_as_float(p1 & 0xffff0000u);
                const float r4 = ua[nt][2].x - __uint_as_float(p2 << 16);
                const float r5 = ua[nt][2].y - __uint_as_float(p2 & 0xffff0000u);
                w.x = (int)cvt2bf(r0, r1);
                w.y = (int)cvt2bf(r2, r3);
                w.z = (int)cvt2bf(r4, r5);
            }
            f1[nt] = *(short8*)&w;
            f2[nt] = (lhi == 0) ? f1[nt] : zero8;
        }
        #pragma unroll
        for (int mt = 0; mt < 4; mt++)
            #pragma unroll
            for (int nt = 0; nt < 2; nt++) {
                acc[mt][nt] = __builtin_amdgcn_mfma_f32_16x16x32_bf16(awU[mt][0], f1[nt], acc[mt][nt], 0, 0, 0);
                acc[mt][nt] = __builtin_amdgcn_mfma_f32_16x16x32_bf16(awU[mt][1], f2[nt], acc[mt][nt], 0, 0, 0);
            }

        // cell updates (lane-local): gates = the 4 D-regs of (b, hu)
        #pragma unroll
        for (int mt = 0; mt < 4; mt++)
            #pragma unroll
            for (int nt = 0; nt < 2; nt++) {
                const int p = mt * 2 + nt;
                float h;
                cell_update(acc[mt][nt], c[p], h);
                if (s < 63) {
                    const unsigned pk = cvt2bf(h, h);
                    const float res = h - __uint_as_float(pk << 16);
                    const unsigned pk2 = cvt2bf(res, res);
                    *(unsigned short*)(Hb + waddr[mt][nt]) = (unsigned short)pk;
                    *(unsigned short*)(Hb + waddr[mt][nt] + 16384) = (unsigned short)pk2;
                } else {
                    const int hu = wave * 16 + mt * 4 + lhi;
                    const int b  = nt * 16 + l15;
                    hout[((size_t)dir * B_TOTAL + b0 + b) * 128 + hu] = h;
                }
            }

        if (s < 63) {
            #pragma unroll
            for (int nt = 0; nt < 2; nt++)
                #pragma unroll
                for (int kc = 0; kc < 4; kc++) raddr[nt][kc] ^= 0x2000;
            #pragma unroll
            for (int mt = 0; mt < 4; mt++)
                #pragma unroll
                for (int nt = 0; nt < 2; nt++) waddr[mt][nt] ^= 0x2000;
        }
        __syncthreads();
    }
}

// ---------------- Kernel C: final FC ----------------
__global__ __launch_bounds__(256) void k_final(
    const float* __restrict__ hout,        // [2][B][128]
    const float* __restrict__ device_idx,  // [B]
    const float* __restrict__ fc_w,        // [257]
    const float* __restrict__ fc_b,        // [1]
    float* __restrict__ y)                 // [B]
{
    const int wave = threadIdx.x >> 6;
    const int lane = threadIdx.x & 63;
    const int b = blockIdx.x * 4 + wave;
    const float* hf = hout + (size_t)b * 128;
    const float* hb = hout + ((size_t)B_TOTAL + b) * 128;
    float p = fc_w[1 + lane]        * hf[lane]
            + fc_w[1 + 64 + lane]   * hf[64 + lane]
            + fc_w[129 + lane]      * hb[lane]
            + fc_w[129 + 64 + lane] * hb[64 + lane];
    #pragma unroll
    for (int off = 32; off; off >>= 1) p += __shfl_xor(p, off, 64);
    if (lane == 0) y[b] = p + fc_w[0] * device_idx[b] + fc_b[0];
}

extern "C" void kernel_launch(void* const* d_in, const int* in_sizes, int n_in,
                              void* d_out, int out_size, void* d_ws, size_t ws_size,
                              hipStream_t stream) {
    const float* device_idx = (const float*)d_in[0];
    const float* matrix     = (const float*)d_in[1];
    const float* features   = (const float*)d_in[2];
    const float* Wi_f = (const float*)d_in[3];
    const float* Wh_f = (const float*)d_in[4];
    const float* bi_f = (const float*)d_in[5];
    const float* bh_f = (const float*)d_in[6];
    const float* Wi_b = (const float*)d_in[7];
    const float* Wh_b = (const float*)d_in[8];
    const float* bi_b = (const float*)d_in[9];
    const float* bh_b = (const float*)d_in[10];
    const float* fc_w = (const float*)d_in[11];
    const float* fc_b = (const float*)d_in[12];
    float* out = (float*)d_out;

    float* ws = (float*)d_ws;
    float*          upd  = ws;                               // 1,572,864 floats
    unsigned short* Aw   = (unsigned short*)(ws + 1572864);  // 327,680 ushorts
    float*          hout = ws + 1736704;                     // 1,048,576 floats

    hipLaunchKernelGGL(k_neighbor_mean, dim3(B_TOTAL), dim3(256), 0, stream,
                       matrix, features, upd);
    hipLaunchKernelGGL(k_wprep2, dim3(1280), dim3(256), 0, stream,
                       Wi_f, Wh_f, bi_f, bh_f, Wi_b, Wh_b, bi_b, bh_b, Aw);
    hipLaunchKernelGGL(k_lstm3, dim3(B_TOTAL / MBATCH, 2), dim3(512), 0, stream,
                       upd, Aw, hout);
    hipLaunchKernelGGL(k_final, dim3(B_TOTAL / 4), dim3(256), 0, stream,
                       hout, device_idx, fc_w, fc_b, out);
}